// Round 11
// baseline (112523.108 us; speedup 1.0000x reference)
//
#include <hip/hip_runtime.h>
#include <math.h>

#define BB 128
#define NTR 16384
#define DD 1024
#define PN (BB*NTR)     // 2097152
#define CN (BB*DD)      // 131072
#define HN (NTR*DD)     // 16777216
#define FWD_SLABS 64    // fwd split-K: 64 slabs of CN = 4*PN floats (k-chunk 256)
#define BWD_SLABS 2     // bwd split-K: 2 slabs of PN (k-chunk 512)

typedef short bf16x8 __attribute__((ext_vector_type(8)));
typedef float f32x2  __attribute__((ext_vector_type(2)));
typedef float f32x4v __attribute__((ext_vector_type(4)));

// ---------------- bf16 split helpers ----------------
__device__ __forceinline__ ushort f2bf(float f) {
  uint u = __float_as_uint(f);
  return (ushort)((u + 0x7FFFu + ((u >> 16) & 1u)) >> 16);   // RNE
}
__device__ __forceinline__ float bf2f(ushort h) { return __uint_as_float(((uint)h) << 16); }
__device__ __forceinline__ void split2(float f, ushort& a, ushort& b) {
  a = f2bf(f); float r1 = f - bf2f(a);
  b = f2bf(r1);
}

// ---------------- one-time: 2-way split H (row-major) ----------------
__global__ __launch_bounds__(256) void k_prep(const float* __restrict__ H,
    ushort* __restrict__ H0, ushort* __restrict__ H1)
{
  const size_t i = ((size_t)blockIdx.x * 256 + threadIdx.x) * 4;
  const float4 x = *(const float4*)(H + i);
  ushort a[4], b[4];
  split2(x.x, a[0], b[0]); split2(x.y, a[1], b[1]);
  split2(x.z, a[2], b[2]); split2(x.w, a[3], b[3]);
  *(ushort4*)(H0 + i) = make_ushort4(a[0], a[1], a[2], a[3]);
  *(ushort4*)(H1 + i) = make_ushort4(b[0], b[1], b[2], b[3]);
}

// ---------------- one-time: stats for p == 0 ----------------
// chunk c of each row: max = 0, expsum = 2048
__global__ __launch_bounds__(256) void k_stat0(float* __restrict__ pmx, float* __restrict__ psm) {
  const int i = blockIdx.x * 256 + threadIdx.x;   // 0..1023 = [chunk][row]
  pmx[i] = 0.f;
  psm[i] = 2048.f;
}

// stats combine helper: row stats from 8 chunk partials
__device__ __forceinline__ void combine_stats(const float* __restrict__ pmx,
    const float* __restrict__ psm, int row, float& mx, float& inv)
{
  mx = -INFINITY;
#pragma unroll
  for (int c = 0; c < 8; ++c) mx = fmaxf(mx, pmx[c*128 + row]);
  float s = 0.f;
#pragma unroll
  for (int c = 0; c < 8; ++c) s += psm[c*128 + row] * expf(pmx[c*128 + row] - mx);
  inv = 1.0f / s;
}

// ---------------- final softmax: p -> out (fp32), 512 threads/row ----------------
__global__ __launch_bounds__(512) void k_softmax_f(const float* __restrict__ p,
                                                   float* __restrict__ w) {
  const int row = blockIdx.x, tid = threadIdx.x;
  const float* pr = p + (size_t)row * NTR;
  float x[32]; float mx = -INFINITY;
#pragma unroll
  for (int i = 0; i < 32; ++i) { x[i] = pr[i*512 + tid]; mx = fmaxf(mx, x[i]); }
  __shared__ float red[512];
  red[tid] = mx; __syncthreads();
  for (int s = 256; s > 0; s >>= 1) { if (tid < s) red[tid] = fmaxf(red[tid], red[tid+s]); __syncthreads(); }
  mx = red[0]; __syncthreads();
  float sum = 0.f;
#pragma unroll
  for (int i = 0; i < 32; ++i) { x[i] = expf(x[i] - mx); sum += x[i]; }
  red[tid] = sum; __syncthreads();
  for (int s = 256; s > 0; s >>= 1) { if (tid < s) red[tid] += red[tid+s]; __syncthreads(); }
  const float inv = 1.0f / red[0];
  float* wr = w + (size_t)row * NTR;
#pragma unroll
  for (int i = 0; i < 32; ++i) wr[i*512 + tid] = x[i] * inv;
}

// ---------------- fwd: C(slab) = softmax(p) @ H, w computed on the fly ----------------
// grid (8 n-tiles of 128, 64 k-slabs), block 256, micro 8x8, reg-prefetch.
// LDS A content = w values (same as R10 modulo sum-tree ulp) -> same accumulation order.
__global__ __launch_bounds__(256) void k_fwd_v(const float* __restrict__ p,
    const float* __restrict__ pmx, const float* __restrict__ psm,
    const float* __restrict__ H, float* __restrict__ Cp)
{
  const int nt = blockIdx.x, tid = threadIdx.x;
  const int kbase = blockIdx.y * 256;
  Cp += (size_t)blockIdx.y * CN;
  __shared__ float As[8][128];
  __shared__ float Bs[8][128];
  __shared__ float smx[128], sinv[128];
  if (tid < 128) {
    float mx, inv; combine_stats(pmx, psm, tid, mx, inv);
    smx[tid] = mx; sinv[tid] = inv;
  }
  const int tm = tid >> 4, tn = tid & 15;
  const int m0 = tm * 8, n0 = tn * 8;
  const int mm = tid >> 1, q = tid & 1;
  const int br = tid >> 5, bc = (tid & 31) * 4;
  const float* Asrc = p + (size_t)mm*NTR + kbase + q*4;
  const float* Bsrc = H + (size_t)(kbase+br)*DD + nt*128 + bc;
  __syncthreads();
  const float mxv = smx[mm], invv = sinv[mm];

  f32x2 acc[8][4];
#pragma unroll
  for (int i = 0; i < 8; ++i)
#pragma unroll
    for (int j = 0; j < 4; ++j) acc[i][j] = (f32x2){0.f, 0.f};

  float4 ra = *(const float4*)(Asrc);
  float4 rb = *(const float4*)(Bsrc);
  float4 wa = make_float4(expf(ra.x-mxv)*invv, expf(ra.y-mxv)*invv,
                          expf(ra.z-mxv)*invv, expf(ra.w-mxv)*invv);
  for (int kk = 0; kk < 256; kk += 8) {
    __syncthreads();
    As[q*4+0][mm]=wa.x; As[q*4+1][mm]=wa.y; As[q*4+2][mm]=wa.z; As[q*4+3][mm]=wa.w;
    *(float4*)&Bs[br][bc] = rb;
    __syncthreads();
    if (kk + 8 < 256) {                         // prefetch + convert, hides under compute
      ra = *(const float4*)(Asrc + kk + 8);
      rb = *(const float4*)(Bsrc + (size_t)(kk+8)*DD);
      wa = make_float4(expf(ra.x-mxv)*invv, expf(ra.y-mxv)*invv,
                       expf(ra.z-mxv)*invv, expf(ra.w-mxv)*invv);
    }
#pragma unroll
    for (int k = 0; k < 8; ++k) {
      float a[8];
      *(float4*)&a[0] = *(const float4*)&As[k][m0];
      *(float4*)&a[4] = *(const float4*)&As[k][m0+4];
      f32x2 b[4];
      b[0] = *(const f32x2*)&Bs[k][n0];
      b[1] = *(const f32x2*)&Bs[k][n0+2];
      b[2] = *(const f32x2*)&Bs[k][n0+4];
      b[3] = *(const f32x2*)&Bs[k][n0+6];
#pragma unroll
      for (int i = 0; i < 8; ++i) {
        const f32x2 ai = (f32x2){a[i], a[i]};
#pragma unroll
        for (int j = 0; j < 4; ++j)
          acc[i][j] = __builtin_elementwise_fma(ai, b[j], acc[i][j]);
      }
    }
  }
#pragma unroll
  for (int i = 0; i < 8; ++i) {
    float* dst = Cp + (size_t)(m0+i)*DD + nt*128 + n0;
    *(float4*)dst     = make_float4(acc[i][0].x, acc[i][0].y, acc[i][1].x, acc[i][1].y);
    *(float4*)(dst+4) = make_float4(acc[i][2].x, acc[i][2].y, acc[i][3].x, acc[i][3].y);
  }
}

// ---------------- S2 = 2*(sum_64 slabs - h), emit 2-way splits ----------------
__global__ __launch_bounds__(256) void k_reduce_S2s(const float* __restrict__ X,
    const float* __restrict__ h,
    ushort* __restrict__ s0, ushort* __restrict__ s1)
{
  const size_t off = ((size_t)blockIdx.x * 256 + threadIdx.x) * 2;
  f32x2 s = (f32x2){0.f, 0.f};
#pragma unroll 4
  for (int k = 0; k < FWD_SLABS; ++k) {
    const f32x2 c = *(const f32x2*)(X + (size_t)k * CN + off);
    s.x += c.x; s.y += c.y;
  }
  const f32x2 hh = *(const f32x2*)(h + off);
  float v0 = 2.f*(s.x-hh.x), v1 = 2.f*(s.y-hh.y);
  ushort a0, b0, a1, b1;
  split2(v0, a0, b0); split2(v1, a1, b1);
  *(ushort2*)(s0 + off) = make_ushort2(a0, a1);
  *(ushort2*)(s1 + off) = make_ushort2(b0, b1);
}

// ---------------- bwd 3-product MFMA + fused w-weighted row partials ----------------
// dw(slab) = S2 @ H^T ; rpart[row][ks*256+bn] (transposed for coalesced adam read)
__global__ __launch_bounds__(256, 2) void k_gemm3_bwd(
    const ushort* __restrict__ A0, const ushort* __restrict__ A1,
    const ushort* __restrict__ B0, const ushort* __restrict__ B1,
    const float* __restrict__ p,
    const float* __restrict__ pmx, const float* __restrict__ psm,
    float* __restrict__ C, float* __restrict__ rpart)
{
  __shared__ ushort lds[12288];   // A: 2*[128][32] ; B: 2*[64][32]
  __shared__ float rbuf[128][33];
  __shared__ float smx[128], sinv[128];
  const int tid = threadIdx.x;
  const int lane = tid & 63, wid = tid >> 6;
  const int wm = (wid >> 1) * 64, wn = (wid & 1) * 32;
  const int bn = blockIdx.x, ks = blockIdx.y;
  const int n0 = bn * 64;
  const int kbase = ks * 512;
  C += (size_t)ks * PN;

  const ushort* Ap[2] = {A0, A1};
  const ushort* Bp[2] = {B0, B1};

  f32x4v acc[4][2];
#pragma unroll
  for (int i = 0; i < 4; ++i)
#pragma unroll
    for (int j = 0; j < 2; ++j) acc[i][j] = (f32x4v){0.f, 0.f, 0.f, 0.f};

  for (int kt = 0; kt < 16; ++kt) {
    const int kpos = kbase + (kt << 5);
#pragma unroll
    for (int c = 0; c < 4; ++c) {
      const int L = c*256 + tid;
      const int s = L >> 9, rr = L & 511;
      const int row = rr >> 2, slot = rr & 3;
      const int sl = slot ^ ((row >> 1) & 3);
      const ushort* src = Ap[s] + (size_t)row * DD + kpos + (sl << 3);
      __builtin_amdgcn_global_load_lds((const __attribute__((address_space(1))) void*)src,
          (__attribute__((address_space(3))) void*)&lds[(size_t)(c*256 + (wid << 6)) * 8], 16, 0, 0);
    }
#pragma unroll
    for (int c = 0; c < 2; ++c) {
      const int L = c*256 + tid;
      const int s = L >> 8, rr = L & 255;
      const int row = rr >> 2, slot = rr & 3;
      const int sl = slot ^ ((row >> 1) & 3);
      const ushort* src = Bp[s] + (size_t)(n0 + row) * DD + kpos + (sl << 3);
      __builtin_amdgcn_global_load_lds((const __attribute__((address_space(1))) void*)src,
          (__attribute__((address_space(3))) void*)&lds[8192 + (size_t)(c*256 + (wid << 6)) * 8], 16, 0, 0);
    }
    __syncthreads();

    bf16x8 bf[2][2];
#pragma unroll
    for (int s = 0; s < 2; ++s)
#pragma unroll
      for (int j = 0; j < 2; ++j) {
        const int n = wn + j*16 + (lane & 15);
        const int sl = (lane >> 4) ^ ((n >> 1) & 3);
        bf[s][j] = *(const bf16x8*)&lds[8192 + s*2048 + n*32 + sl*8];
      }
#pragma unroll
    for (int sa = 0; sa < 2; ++sa) {
      bf16x8 af[4];
#pragma unroll
      for (int i = 0; i < 4; ++i) {
        const int mrow = wm + i*16 + (lane & 15);
        const int sl = (lane >> 4) ^ ((mrow >> 1) & 3);
        af[i] = *(const bf16x8*)&lds[sa*4096 + mrow*32 + sl*8];
      }
#pragma unroll
      for (int sb = 0; sb < 2 - sa; ++sb)
#pragma unroll
        for (int i = 0; i < 4; ++i)
#pragma unroll
          for (int j = 0; j < 2; ++j)
            acc[i][j] = __builtin_amdgcn_mfma_f32_16x16x32_bf16(af[i], bf[sb][j], acc[i][j], 0, 0, 0);
    }
    __syncthreads();
  }
  // row stats for on-the-fly w in epilogue
  if (tid < 128) {
    float mx, inv; combine_stats(pmx, psm, tid, mx, inv);
    smx[tid] = mx; sinv[tid] = inv;
  }
  __syncthreads();
  // epilogue: store dw slab + fused w-weighted row partials
#pragma unroll
  for (int i = 0; i < 4; ++i) {
    const int rbase = wm + i*16 + ((lane >> 4) << 2);
#pragma unroll
    for (int r = 0; r < 4; ++r) {
      const int row = rbase + r;
      const float mxv = smx[row], invv = sinv[row];
      float s = 0.f;
#pragma unroll
      for (int j = 0; j < 2; ++j) {
        const int cg = n0 + wn + j*16 + (lane & 15);
        C[(size_t)row * NTR + cg] = acc[i][j][r];
        const float wv = expf(p[(size_t)row * NTR + cg] - mxv) * invv;
        s = fmaf(wv, acc[i][j][r], s);
      }
      rbuf[row][((wn >> 5) << 4) + (lane & 15)] = s;
    }
  }
  __syncthreads();
  if (tid < 128) {
    float s = 0.f;
#pragma unroll
    for (int t = 0; t < 32; ++t) s += rbuf[tid][t];
    rpart[(size_t)tid * 512 + ks*256 + bn] = s;
  }
}

// ---------------- Adam: w on the fly, update p,m,v, emit new chunk stats ----------------
__global__ __launch_bounds__(256) void k_adam_f(float* __restrict__ pp_,
    float* __restrict__ m, float* __restrict__ v,
    const float* __restrict__ X, const float* __restrict__ rpart,
    const float* __restrict__ pmx_in, const float* __restrict__ psm_in,
    float* __restrict__ pmx_out, float* __restrict__ psm_out,
    float bc1, float bc2)
{
  const int bid = blockIdx.x, tid = threadIdx.x;
  const int row = bid >> 3, chunk = bid & 7;
  float mx, inv; combine_stats(pmx_in, psm_in, row, mx, inv);
  __shared__ float red[256];
  red[tid] = rpart[(size_t)row*512 + tid] + rpart[(size_t)row*512 + 256 + tid];
  __syncthreads();
  for (int s = 128; s > 0; s >>= 1) { if (tid < s) red[tid] += red[tid+s]; __syncthreads(); }
  const float rr = red[0];
  const size_t base = (size_t)bid * 2048 + tid * 4;
  float pn[8];
#pragma unroll
  for (int part = 0; part < 2; ++part) {
    const size_t off = base + part * 1024;
    float4 u  = *(const float4*)(X + off);
    const float4 u1 = *(const float4*)(X + (size_t)PN + off);
    u.x += u1.x; u.y += u1.y; u.z += u1.z; u.w += u1.w;
    const float uu[4] = {u.x, u.y, u.z, u.w};
    float4 p4 = *(float4*)(pp_ + off);
    float4 m4 = *(float4*)(m + off);
    float4 v4 = *(float4*)(v + off);
    float* pp = (float*)&p4; float* mm = (float*)&m4; float* vv = (float*)&v4;
#pragma unroll
    for (int e = 0; e < 4; ++e) {
      const float wv = expf(pp[e] - mx) * inv;     // w from OLD p
      const float g  = wv * (uu[e] - rr);
      const float mn = 0.9f*mm[e] + 0.1f*g;
      const float vn = 0.999f*vv[e] + 0.001f*(g*g);
      const float mh = mn / bc1, vh = vn / bc2;
      pp[e] = pp[e] - 1e-3f * mh / (sqrtf(vh) + 1e-8f);
      mm[e] = mn; vv[e] = vn;
      pn[part*4 + e] = pp[e];
    }
    *(float4*)(pp_ + off) = p4;
    *(float4*)(m + off) = m4;
    *(float4*)(v + off) = v4;
  }
  // new chunk stats over the 2048 updated p values
  float lmx = pn[0];
#pragma unroll
  for (int e = 1; e < 8; ++e) lmx = fmaxf(lmx, pn[e]);
  __syncthreads();
  red[tid] = lmx; __syncthreads();
  for (int s = 128; s > 0; s >>= 1) { if (tid < s) red[tid] = fmaxf(red[tid], red[tid+s]); __syncthreads(); }
  const float bmx = red[0]; __syncthreads();
  float ls = 0.f;
#pragma unroll
  for (int e = 0; e < 8; ++e) ls += expf(pn[e] - bmx);
  red[tid] = ls; __syncthreads();
  for (int s = 128; s > 0; s >>= 1) { if (tid < s) red[tid] += red[tid+s]; __syncthreads(); }
  if (tid == 0) {
    pmx_out[chunk*128 + row] = bmx;
    psm_out[chunk*128 + row] = red[0];
  }
}

extern "C" void kernel_launch(void* const* d_in, const int* in_sizes, int n_in,
                              void* d_out, int out_size, void* d_ws, size_t ws_size,
                              hipStream_t stream) {
  const float* h = (const float*)d_in[0];
  const float* H = (const float*)d_in[1];
  (void)in_sizes; (void)n_in; (void)out_size; (void)ws_size;
  const int n_epoch = 1000;

  // floats: p,m,v (3PN) + X (4PN) + rpart (128*512) + stats A/B (4*1024)
  // ushorts: s-splits (2CN) + H-splits (2HN)   -> ~128 MB
  float* p  = (float*)d_ws;
  float* m  = p + PN;
  float* v  = m + PN;
  float* X  = v + PN;
  float* rp = X + (size_t)4*PN;          // 128*512
  float* pmxA = rp + 128*512;            // 1024
  float* psmA = pmxA + 1024;
  float* pmxB = psmA + 1024;
  float* psmB = pmxB + 1024;
  ushort* s0 = (ushort*)(psmB + 1024);
  ushort* s1 = s0 + CN;
  ushort* H0 = s1 + CN, *H1 = H0 + HN;

  hipMemsetAsync(p, 0, (size_t)3*PN*sizeof(float), stream);
  k_prep<<<HN/1024, 256, 0, stream>>>(H, H0, H1);
  k_stat0<<<4, 256, 0, stream>>>(pmxA, psmA);

  for (int s = 1; s <= n_epoch; ++s) {
    float* pmx_in  = (s & 1) ? pmxA : pmxB;
    float* psm_in  = (s & 1) ? psmA : psmB;
    float* pmx_out = (s & 1) ? pmxB : pmxA;
    float* psm_out = (s & 1) ? psmB : psmA;
    k_fwd_v<<<dim3(8, FWD_SLABS), 256, 0, stream>>>(p, pmx_in, psm_in, H, X);
    k_reduce_S2s<<<CN/512, 256, 0, stream>>>(X, h, s0, s1);
    k_gemm3_bwd<<<dim3(256, BWD_SLABS), 256, 0, stream>>>(s0, s1, H0, H1, p, pmx_in, psm_in, X, rp);
    const float bc1 = 1.0f - powf(0.9f,   (float)s);
    const float bc2 = 1.0f - powf(0.999f, (float)s);
    k_adam_f<<<1024, 256, 0, stream>>>(p, m, v, X, rp, pmx_in, psm_in, pmx_out, psm_out, bc1, bc2);
  }
  k_softmax_f<<<BB, 512, 0, stream>>>(p, (float*)d_out);
}

// Round 12
// 110452.502 us; speedup vs baseline: 1.0187x; 1.0187x over previous
//
#include <hip/hip_runtime.h>
#include <math.h>

#define BB 128
#define NTR 16384
#define DD 1024
#define PN (BB*NTR)     // 2097152
#define CN (BB*DD)      // 131072
#define HN (NTR*DD)     // 16777216
#define FWD_SLABS 64    // fwd split-K: 64 slabs of CN = 4*PN floats (k-chunk 256)
#define BWD_SLABS 2     // bwd split-K: 2 slabs of PN (k-chunk 512)

typedef short bf16x8 __attribute__((ext_vector_type(8)));
typedef float f32x2  __attribute__((ext_vector_type(2)));
typedef float f32x4v __attribute__((ext_vector_type(4)));

// ---------------- bf16 split helpers ----------------
__device__ __forceinline__ ushort f2bf(float f) {
  uint u = __float_as_uint(f);
  return (ushort)((u + 0x7FFFu + ((u >> 16) & 1u)) >> 16);   // RNE
}
__device__ __forceinline__ float bf2f(ushort h) { return __uint_as_float(((uint)h) << 16); }
__device__ __forceinline__ void split2(float f, ushort& a, ushort& b) {
  a = f2bf(f); float r1 = f - bf2f(a);
  b = f2bf(r1);
}

// ---------------- one-time: 2-way split H (row-major) ----------------
__global__ __launch_bounds__(256) void k_prep(const float* __restrict__ H,
    ushort* __restrict__ H0, ushort* __restrict__ H1)
{
  const size_t i = ((size_t)blockIdx.x * 256 + threadIdx.x) * 4;
  const float4 x = *(const float4*)(H + i);
  ushort a[4], b[4];
  split2(x.x, a[0], b[0]); split2(x.y, a[1], b[1]);
  split2(x.z, a[2], b[2]); split2(x.w, a[3], b[3]);
  *(ushort4*)(H0 + i) = make_ushort4(a[0], a[1], a[2], a[3]);
  *(ushort4*)(H1 + i) = make_ushort4(b[0], b[1], b[2], b[3]);
}

// ---------------- one-time: stats for p == 0 (max=0, expsum=2048 per chunk) ----------------
__global__ __launch_bounds__(256) void k_stat0(float* __restrict__ pmx, float* __restrict__ psm) {
  const int i = blockIdx.x * 256 + threadIdx.x;   // [chunk][row], 8*128
  pmx[i] = 0.f;
  psm[i] = 2048.f;
}

// row stats from 8 chunk partials
__device__ __forceinline__ void combine_stats(const float* __restrict__ pmx,
    const float* __restrict__ psm, int row, float& mx, float& inv)
{
  mx = -INFINITY;
#pragma unroll
  for (int c = 0; c < 8; ++c) mx = fmaxf(mx, pmx[c*128 + row]);
  float s = 0.f;
#pragma unroll
  for (int c = 0; c < 8; ++c) s += psm[c*128 + row] * expf(pmx[c*128 + row] - mx);
  inv = 1.0f / s;
}

// ---------------- per-step: materialize w = exp(p - mx) * inv (1-pass) ----------------
__global__ __launch_bounds__(256) void k_wmat(const float* __restrict__ p,
    const float* __restrict__ pmx, const float* __restrict__ psm,
    float* __restrict__ w)
{
  const int bid = blockIdx.x, tid = threadIdx.x;
  const int row = bid >> 3;
  float mx, inv; combine_stats(pmx, psm, row, mx, inv);
  const size_t base = (size_t)bid * 2048 + tid * 8;
  const float4 a = *(const float4*)(p + base);
  const float4 b = *(const float4*)(p + base + 4);
  *(float4*)(w + base)     = make_float4(expf(a.x-mx)*inv, expf(a.y-mx)*inv,
                                         expf(a.z-mx)*inv, expf(a.w-mx)*inv);
  *(float4*)(w + base + 4) = make_float4(expf(b.x-mx)*inv, expf(b.y-mx)*inv,
                                         expf(b.z-mx)*inv, expf(b.w-mx)*inv);
}

// ---------------- final softmax: p -> out (fp32), 512 threads/row ----------------
__global__ __launch_bounds__(512) void k_softmax_f(const float* __restrict__ p,
                                                   float* __restrict__ w) {
  const int row = blockIdx.x, tid = threadIdx.x;
  const float* pr = p + (size_t)row * NTR;
  float x[32]; float mx = -INFINITY;
#pragma unroll
  for (int i = 0; i < 32; ++i) { x[i] = pr[i*512 + tid]; mx = fmaxf(mx, x[i]); }
  __shared__ float red[512];
  red[tid] = mx; __syncthreads();
  for (int s = 256; s > 0; s >>= 1) { if (tid < s) red[tid] = fmaxf(red[tid], red[tid+s]); __syncthreads(); }
  mx = red[0]; __syncthreads();
  float sum = 0.f;
#pragma unroll
  for (int i = 0; i < 32; ++i) { x[i] = expf(x[i] - mx); sum += x[i]; }
  red[tid] = sum; __syncthreads();
  for (int s = 256; s > 0; s >>= 1) { if (tid < s) red[tid] += red[tid+s]; __syncthreads(); }
  const float inv = 1.0f / red[0];
  float* wr = w + (size_t)row * NTR;
#pragma unroll
  for (int i = 0; i < 32; ++i) wr[i*512 + tid] = x[i] * inv;
}

// ---------------- VALU fp32 forward, double-buffered LDS + reg-prefetch ----------------
// grid (8 n-tiles of 128, 64 k-slabs) = 512 blocks, block 256, micro 8x8.
// Per-output k-order identical to R10 -> bit-identical C.
__global__ __launch_bounds__(256) void k_fwd_v(const float* __restrict__ w,
    const float* __restrict__ H, float* __restrict__ Cp)
{
  const int nt = blockIdx.x, tid = threadIdx.x;
  const int kbase = blockIdx.y * 256;
  Cp += (size_t)blockIdx.y * CN;
  __shared__ float As[2][8][128];
  __shared__ float Bs[2][8][128];
  const int tm = tid >> 4, tn = tid & 15;
  const int m0 = tm * 8, n0 = tn * 8;
  const int mm = tid >> 1, q = tid & 1;
  const int br = tid >> 5, bc = (tid & 31) * 4;
  const float* Asrc = w + (size_t)mm*NTR + kbase + q*4;
  const float* Bsrc = H + (size_t)(kbase+br)*DD + nt*128 + bc;

  f32x2 acc[8][4];
#pragma unroll
  for (int i = 0; i < 8; ++i)
#pragma unroll
    for (int j = 0; j < 4; ++j) acc[i][j] = (f32x2){0.f, 0.f};

  // prologue: stage t=0 into buf0, prefetch t=1 into regs
  float4 ra = *(const float4*)(Asrc);
  float4 rb = *(const float4*)(Bsrc);
  As[0][q*4+0][mm]=ra.x; As[0][q*4+1][mm]=ra.y; As[0][q*4+2][mm]=ra.z; As[0][q*4+3][mm]=ra.w;
  *(float4*)&Bs[0][br][bc] = rb;
  ra = *(const float4*)(Asrc + 8);
  rb = *(const float4*)(Bsrc + (size_t)8*DD);

  for (int t = 0; t < 32; ++t) {
    const int cur = t & 1;
    __syncthreads();                        // buf[cur] ready; buf[cur^1] free
    if (t + 1 < 32) {
      As[cur^1][q*4+0][mm]=ra.x; As[cur^1][q*4+1][mm]=ra.y;
      As[cur^1][q*4+2][mm]=ra.z; As[cur^1][q*4+3][mm]=ra.w;
      *(float4*)&Bs[cur^1][br][bc] = rb;
    }
    if (t + 2 < 32) {                       // prefetch t+2, hides under compute
      ra = *(const float4*)(Asrc + (t+2)*8);
      rb = *(const float4*)(Bsrc + (size_t)((t+2)*8)*DD);
    }
#pragma unroll
    for (int k = 0; k < 8; ++k) {
      float a[8];
      *(float4*)&a[0] = *(const float4*)&As[cur][k][m0];
      *(float4*)&a[4] = *(const float4*)&As[cur][k][m0+4];
      f32x2 b[4];
      b[0] = *(const f32x2*)&Bs[cur][k][n0];
      b[1] = *(const f32x2*)&Bs[cur][k][n0+2];
      b[2] = *(const f32x2*)&Bs[cur][k][n0+4];
      b[3] = *(const f32x2*)&Bs[cur][k][n0+6];
#pragma unroll
      for (int i = 0; i < 8; ++i) {
        const f32x2 ai = (f32x2){a[i], a[i]};
#pragma unroll
        for (int j = 0; j < 4; ++j)
          acc[i][j] = __builtin_elementwise_fma(ai, b[j], acc[i][j]);
      }
    }
  }
#pragma unroll
  for (int i = 0; i < 8; ++i) {
    float* dst = Cp + (size_t)(m0+i)*DD + nt*128 + n0;
    *(float4*)dst     = make_float4(acc[i][0].x, acc[i][0].y, acc[i][1].x, acc[i][1].y);
    *(float4*)(dst+4) = make_float4(acc[i][2].x, acc[i][2].y, acc[i][3].x, acc[i][3].y);
  }
}

// ---------------- S2 = 2*(sum_64 slabs - h), emit 2-way splits ----------------
__global__ __launch_bounds__(256) void k_reduce_S2s(const float* __restrict__ X,
    const float* __restrict__ h,
    ushort* __restrict__ s0, ushort* __restrict__ s1)
{
  const size_t off = ((size_t)blockIdx.x * 256 + threadIdx.x) * 2;
  f32x2 s = (f32x2){0.f, 0.f};
#pragma unroll 4
  for (int k = 0; k < FWD_SLABS; ++k) {
    const f32x2 c = *(const f32x2*)(X + (size_t)k * CN + off);
    s.x += c.x; s.y += c.y;
  }
  const f32x2 hh = *(const f32x2*)(h + off);
  float v0 = 2.f*(s.x-hh.x), v1 = 2.f*(s.y-hh.y);
  ushort a0, b0, a1, b1;
  split2(v0, a0, b0); split2(v1, a1, b1);
  *(ushort2*)(s0 + off) = make_ushort2(a0, a1);
  *(ushort2*)(s1 + off) = make_ushort2(b0, b1);
}

// ---------------- bwd 3-product MFMA + fused w-weighted row partials ----------------
// dw(slab) = S2 @ H^T ; rpart[row][ks*256+bn] (transposed for coalesced adam read)
__global__ __launch_bounds__(256, 2) void k_gemm3_bwd(
    const ushort* __restrict__ A0, const ushort* __restrict__ A1,
    const ushort* __restrict__ B0, const ushort* __restrict__ B1,
    const float* __restrict__ w,
    float* __restrict__ C, float* __restrict__ rpart)
{
  __shared__ ushort lds[12288];   // A: 2*[128][32] ; B: 2*[64][32]
  __shared__ float rbuf[128][33];
  const int tid = threadIdx.x;
  const int lane = tid & 63, wid = tid >> 6;
  const int wm = (wid >> 1) * 64, wn = (wid & 1) * 32;
  const int bn = blockIdx.x, ks = blockIdx.y;
  const int n0 = bn * 64;
  const int kbase = ks * 512;
  C += (size_t)ks * PN;

  const ushort* Ap[2] = {A0, A1};
  const ushort* Bp[2] = {B0, B1};

  f32x4v acc[4][2];
#pragma unroll
  for (int i = 0; i < 4; ++i)
#pragma unroll
    for (int j = 0; j < 2; ++j) acc[i][j] = (f32x4v){0.f, 0.f, 0.f, 0.f};

  for (int kt = 0; kt < 16; ++kt) {
    const int kpos = kbase + (kt << 5);
#pragma unroll
    for (int c = 0; c < 4; ++c) {
      const int L = c*256 + tid;
      const int s = L >> 9, rr = L & 511;
      const int row = rr >> 2, slot = rr & 3;
      const int sl = slot ^ ((row >> 1) & 3);
      const ushort* src = Ap[s] + (size_t)row * DD + kpos + (sl << 3);
      __builtin_amdgcn_global_load_lds((const __attribute__((address_space(1))) void*)src,
          (__attribute__((address_space(3))) void*)&lds[(size_t)(c*256 + (wid << 6)) * 8], 16, 0, 0);
    }
#pragma unroll
    for (int c = 0; c < 2; ++c) {
      const int L = c*256 + tid;
      const int s = L >> 8, rr = L & 255;
      const int row = rr >> 2, slot = rr & 3;
      const int sl = slot ^ ((row >> 1) & 3);
      const ushort* src = Bp[s] + (size_t)(n0 + row) * DD + kpos + (sl << 3);
      __builtin_amdgcn_global_load_lds((const __attribute__((address_space(1))) void*)src,
          (__attribute__((address_space(3))) void*)&lds[8192 + (size_t)(c*256 + (wid << 6)) * 8], 16, 0, 0);
    }
    __syncthreads();

    bf16x8 bf[2][2];
#pragma unroll
    for (int s = 0; s < 2; ++s)
#pragma unroll
      for (int j = 0; j < 2; ++j) {
        const int n = wn + j*16 + (lane & 15);
        const int sl = (lane >> 4) ^ ((n >> 1) & 3);
        bf[s][j] = *(const bf16x8*)&lds[8192 + s*2048 + n*32 + sl*8];
      }
#pragma unroll
    for (int sa = 0; sa < 2; ++sa) {
      bf16x8 af[4];
#pragma unroll
      for (int i = 0; i < 4; ++i) {
        const int mrow = wm + i*16 + (lane & 15);
        const int sl = (lane >> 4) ^ ((mrow >> 1) & 3);
        af[i] = *(const bf16x8*)&lds[sa*4096 + mrow*32 + sl*8];
      }
#pragma unroll
      for (int sb = 0; sb < 2 - sa; ++sb)
#pragma unroll
        for (int i = 0; i < 4; ++i)
#pragma unroll
          for (int j = 0; j < 2; ++j)
            acc[i][j] = __builtin_amdgcn_mfma_f32_16x16x32_bf16(af[i], bf[sb][j], acc[i][j], 0, 0, 0);
    }
    __syncthreads();
  }
  // epilogue: store dw slab + fused w-weighted row partials
#pragma unroll
  for (int i = 0; i < 4; ++i) {
    const int rbase = wm + i*16 + ((lane >> 4) << 2);
#pragma unroll
    for (int r = 0; r < 4; ++r) {
      const int row = rbase + r;
      float s = 0.f;
#pragma unroll
      for (int j = 0; j < 2; ++j) {
        const int cg = n0 + wn + j*16 + (lane & 15);
        C[(size_t)row * NTR + cg] = acc[i][j][r];
        s = fmaf(w[(size_t)row * NTR + cg], acc[i][j][r], s);
      }
      rbuf[row][((wn >> 5) << 4) + (lane & 15)] = s;
    }
  }
  __syncthreads();
  if (tid < 128) {
    float s = 0.f;
#pragma unroll
    for (int t = 0; t < 32; ++t) s += rbuf[tid][t];
    rpart[(size_t)tid * 512 + ks*256 + bn] = s;
  }
}

// ---------------- Adam: reads w, updates p,m,v, emits new chunk stats ----------------
__global__ __launch_bounds__(256) void k_adam_f(float* __restrict__ pp_,
    float* __restrict__ m, float* __restrict__ v,
    const float* __restrict__ w, const float* __restrict__ X,
    const float* __restrict__ rpart,
    float* __restrict__ pmx_out, float* __restrict__ psm_out,
    float bc1, float bc2)
{
  const int bid = blockIdx.x, tid = threadIdx.x;
  const int row = bid >> 3, chunk = bid & 7;
  __shared__ float red[256];
  red[tid] = rpart[(size_t)row*512 + tid] + rpart[(size_t)row*512 + 256 + tid];
  __syncthreads();
  for (int s = 128; s > 0; s >>= 1) { if (tid < s) red[tid] += red[tid+s]; __syncthreads(); }
  const float rr = red[0];
  const size_t base = (size_t)bid * 2048 + tid * 4;
  float pn[8];
#pragma unroll
  for (int part = 0; part < 2; ++part) {
    const size_t off = base + part * 1024;
    float4 u  = *(const float4*)(X + off);
    const float4 u1 = *(const float4*)(X + (size_t)PN + off);
    u.x += u1.x; u.y += u1.y; u.z += u1.z; u.w += u1.w;
    const float4 w4 = *(const float4*)(w + off);
    const float wv[4] = {w4.x, w4.y, w4.z, w4.w};
    const float uu[4] = {u.x, u.y, u.z, u.w};
    float4 p4 = *(float4*)(pp_ + off);
    float4 m4 = *(float4*)(m + off);
    float4 v4 = *(float4*)(v + off);
    float* pp = (float*)&p4; float* mm = (float*)&m4; float* vv = (float*)&v4;
#pragma unroll
    for (int e = 0; e < 4; ++e) {
      const float g  = wv[e] * (uu[e] - rr);
      const float mn = 0.9f*mm[e] + 0.1f*g;
      const float vn = 0.999f*vv[e] + 0.001f*(g*g);
      const float mh = mn / bc1, vh = vn / bc2;
      pp[e] = pp[e] - 1e-3f * mh / (sqrtf(vh) + 1e-8f);
      mm[e] = mn; vv[e] = vn;
      pn[part*4 + e] = pp[e];
    }
    *(float4*)(pp_ + off) = p4;
    *(float4*)(m + off) = m4;
    *(float4*)(v + off) = v4;
  }
  // new chunk stats over the 2048 updated p values
  float lmx = pn[0];
#pragma unroll
  for (int e = 1; e < 8; ++e) lmx = fmaxf(lmx, pn[e]);
  __syncthreads();
  red[tid] = lmx; __syncthreads();
  for (int s = 128; s > 0; s >>= 1) { if (tid < s) red[tid] = fmaxf(red[tid], red[tid+s]); __syncthreads(); }
  const float bmx = red[0]; __syncthreads();
  float ls = 0.f;
#pragma unroll
  for (int e = 0; e < 8; ++e) ls += expf(pn[e] - bmx);
  red[tid] = ls; __syncthreads();
  for (int s = 128; s > 0; s >>= 1) { if (tid < s) red[tid] += red[tid+s]; __syncthreads(); }
  if (tid == 0) {
    pmx_out[chunk*128 + row] = bmx;
    psm_out[chunk*128 + row] = red[0];
  }
}

extern "C" void kernel_launch(void* const* d_in, const int* in_sizes, int n_in,
                              void* d_out, int out_size, void* d_ws, size_t ws_size,
                              hipStream_t stream) {
  const float* h = (const float*)d_in[0];
  const float* H = (const float*)d_in[1];
  (void)in_sizes; (void)n_in; (void)out_size; (void)ws_size;
  const int n_epoch = 1000;

  // floats: p,m,v (3PN) + w (PN) + X (4PN) + rpart (128*512) + stats A/B (4*1024)
  // ushorts: s-splits (2CN) + H-splits (2HN)   -> ~135 MB
  float* p  = (float*)d_ws;
  float* m  = p + PN;
  float* v  = m + PN;
  float* w  = v + PN;
  float* X  = w + PN;
  float* rp = X + (size_t)4*PN;          // 128*512
  float* pmxA = rp + 128*512;            // 1024 each
  float* psmA = pmxA + 1024;
  float* pmxB = psmA + 1024;
  float* psmB = pmxB + 1024;
  ushort* s0 = (ushort*)(psmB + 1024);
  ushort* s1 = s0 + CN;
  ushort* H0 = s1 + CN, *H1 = H0 + HN;

  hipMemsetAsync(p, 0, (size_t)3*PN*sizeof(float), stream);
  k_prep<<<HN/1024, 256, 0, stream>>>(H, H0, H1);
  k_stat0<<<4, 256, 0, stream>>>(pmxA, psmA);

  for (int s = 1; s <= n_epoch; ++s) {
    float* pmx_in  = (s & 1) ? pmxA : pmxB;
    float* psm_in  = (s & 1) ? psmA : psmB;
    float* pmx_out = (s & 1) ? pmxB : pmxA;
    float* psm_out = (s & 1) ? psmB : psmA;
    k_wmat<<<PN/2048, 256, 0, stream>>>(p, pmx_in, psm_in, w);
    k_fwd_v<<<dim3(8, FWD_SLABS), 256, 0, stream>>>(w, H, X);
    k_reduce_S2s<<<CN/512, 256, 0, stream>>>(X, h, s0, s1);
    k_gemm3_bwd<<<dim3(256, BWD_SLABS), 256, 0, stream>>>(s0, s1, H0, H1, w, X, rp);
    const float bc1 = 1.0f - powf(0.9f,   (float)s);
    const float bc2 = 1.0f - powf(0.999f, (float)s);
    k_adam_f<<<1024, 256, 0, stream>>>(p, m, v, w, X, rp, pmx_out, psm_out, bc1, bc2);
  }
  k_softmax_f<<<BB, 512, 0, stream>>>(p, (float*)d_out);
}

// Round 13
// 106520.740 us; speedup vs baseline: 1.0563x; 1.0369x over previous
//
#include <hip/hip_runtime.h>
#include <math.h>

#define BB 128
#define NTR 16384
#define DD 1024
#define PN (BB*NTR)     // 2097152
#define CN (BB*DD)      // 131072
#define HN (NTR*DD)     // 16777216
#define FWD_SLABS 64    // fwd split-K: 64 slabs of CN = 4*PN floats (k-chunk 256)
#define BWD_SLABS 2     // bwd split-K: 2 slabs of PN (k-chunk 512)

typedef short bf16x8 __attribute__((ext_vector_type(8)));
typedef float f32x2  __attribute__((ext_vector_type(2)));
typedef float f32x4v __attribute__((ext_vector_type(4)));

// ---------------- bf16 split helpers ----------------
__device__ __forceinline__ ushort f2bf(float f) {
  uint u = __float_as_uint(f);
  return (ushort)((u + 0x7FFFu + ((u >> 16) & 1u)) >> 16);   // RNE
}
__device__ __forceinline__ float bf2f(ushort h) { return __uint_as_float(((uint)h) << 16); }
__device__ __forceinline__ void split2(float f, ushort& a, ushort& b) {
  a = f2bf(f); float r1 = f - bf2f(a);
  b = f2bf(r1);
}

// ---------------- one-time: 2-way split H (row-major) ----------------
__global__ __launch_bounds__(256) void k_prep(const float* __restrict__ H,
    ushort* __restrict__ H0, ushort* __restrict__ H1)
{
  const size_t i = ((size_t)blockIdx.x * 256 + threadIdx.x) * 4;
  const float4 x = *(const float4*)(H + i);
  ushort a[4], b[4];
  split2(x.x, a[0], b[0]); split2(x.y, a[1], b[1]);
  split2(x.z, a[2], b[2]); split2(x.w, a[3], b[3]);
  *(ushort4*)(H0 + i) = make_ushort4(a[0], a[1], a[2], a[3]);
  *(ushort4*)(H1 + i) = make_ushort4(b[0], b[1], b[2], b[3]);
}

// ---------------- one-time: stats + e for p == 0 ----------------
// p=0: chunk max=0, chunk expsum=2048, e=exp(0-0)=1 everywhere
__global__ __launch_bounds__(256) void k_stat0(float* __restrict__ pmx, float* __restrict__ psm) {
  const int i = blockIdx.x * 256 + threadIdx.x;   // [chunk][row], 8*128
  pmx[i] = 0.f;
  psm[i] = 2048.f;
}
__global__ __launch_bounds__(256) void k_einit(float* __restrict__ e) {
  const size_t base = (size_t)blockIdx.x * 2048 + threadIdx.x * 8;
  const float4 one = make_float4(1.f, 1.f, 1.f, 1.f);
  *(float4*)(e + base) = one;
  *(float4*)(e + base + 4) = one;
}

// row stats from 8 chunk partials
__device__ __forceinline__ void combine_stats(const float* __restrict__ pmx,
    const float* __restrict__ psm, int row, float& mx, float& inv)
{
  mx = -INFINITY;
#pragma unroll
  for (int c = 0; c < 8; ++c) mx = fmaxf(mx, pmx[c*128 + row]);
  float s = 0.f;
#pragma unroll
  for (int c = 0; c < 8; ++c) s += psm[c*128 + row] * expf(pmx[c*128 + row] - mx);
  inv = 1.0f / s;
}

// ---------------- final softmax: p -> out (fp32), 512 threads/row ----------------
__global__ __launch_bounds__(512) void k_softmax_f(const float* __restrict__ p,
                                                   float* __restrict__ w) {
  const int row = blockIdx.x, tid = threadIdx.x;
  const float* pr = p + (size_t)row * NTR;
  float x[32]; float mx = -INFINITY;
#pragma unroll
  for (int i = 0; i < 32; ++i) { x[i] = pr[i*512 + tid]; mx = fmaxf(mx, x[i]); }
  __shared__ float red[512];
  red[tid] = mx; __syncthreads();
  for (int s = 256; s > 0; s >>= 1) { if (tid < s) red[tid] = fmaxf(red[tid], red[tid+s]); __syncthreads(); }
  mx = red[0]; __syncthreads();
  float sum = 0.f;
#pragma unroll
  for (int i = 0; i < 32; ++i) { x[i] = expf(x[i] - mx); sum += x[i]; }
  red[tid] = sum; __syncthreads();
  for (int s = 256; s > 0; s >>= 1) { if (tid < s) red[tid] += red[tid+s]; __syncthreads(); }
  const float inv = 1.0f / red[0];
  float* wr = w + (size_t)row * NTR;
#pragma unroll
  for (int i = 0; i < 32; ++i) wr[i*512 + tid] = x[i] * inv;
}

// ---------------- VALU fp32 forward: C(slab) = (e*scale) @ H ----------------
// grid (8 n-tiles of 128, 64 k-slabs) = 512 blocks, block 256, micro 8x8, dbuf+prefetch.
// w = e[row][k] * scale[row] (scale per (row, 2048-chunk); chunk constant per block).
__global__ __launch_bounds__(256) void k_fwd_v(const float* __restrict__ e,
    const float* __restrict__ pmx, const float* __restrict__ psm,
    const float* __restrict__ H, float* __restrict__ Cp)
{
  const int nt = blockIdx.x, tid = threadIdx.x;
  const int kbase = blockIdx.y * 256;
  const int chunk = kbase >> 11;
  Cp += (size_t)blockIdx.y * CN;
  __shared__ float As[2][8][128];
  __shared__ float Bs[2][8][128];
  __shared__ float sscale[128];
  if (tid < 128) {
    float mx, inv; combine_stats(pmx, psm, tid, mx, inv);
    sscale[tid] = expf(pmx[chunk*128 + tid] - mx) * inv;
  }
  const int tm = tid >> 4, tn = tid & 15;
  const int m0 = tm * 8, n0 = tn * 8;
  const int mm = tid >> 1, q = tid & 1;
  const int br = tid >> 5, bc = (tid & 31) * 4;
  const float* Asrc = e + (size_t)mm*NTR + kbase + q*4;
  const float* Bsrc = H + (size_t)(kbase+br)*DD + nt*128 + bc;
  __syncthreads();
  const float sA = sscale[mm];

  f32x2 acc[8][4];
#pragma unroll
  for (int i = 0; i < 8; ++i)
#pragma unroll
    for (int j = 0; j < 4; ++j) acc[i][j] = (f32x2){0.f, 0.f};

  // prologue: stage t=0 into buf0, prefetch t=1
  float4 ra = *(const float4*)(Asrc);
  float4 rb = *(const float4*)(Bsrc);
  As[0][q*4+0][mm]=ra.x*sA; As[0][q*4+1][mm]=ra.y*sA;
  As[0][q*4+2][mm]=ra.z*sA; As[0][q*4+3][mm]=ra.w*sA;
  *(float4*)&Bs[0][br][bc] = rb;
  ra = *(const float4*)(Asrc + 8);
  rb = *(const float4*)(Bsrc + (size_t)8*DD);

  for (int t = 0; t < 32; ++t) {
    const int cur = t & 1;
    __syncthreads();
    if (t + 1 < 32) {
      As[cur^1][q*4+0][mm]=ra.x*sA; As[cur^1][q*4+1][mm]=ra.y*sA;
      As[cur^1][q*4+2][mm]=ra.z*sA; As[cur^1][q*4+3][mm]=ra.w*sA;
      *(float4*)&Bs[cur^1][br][bc] = rb;
    }
    if (t + 2 < 32) {
      ra = *(const float4*)(Asrc + (t+2)*8);
      rb = *(const float4*)(Bsrc + (size_t)((t+2)*8)*DD);
    }
#pragma unroll
    for (int k = 0; k < 8; ++k) {
      float a[8];
      *(float4*)&a[0] = *(const float4*)&As[cur][k][m0];
      *(float4*)&a[4] = *(const float4*)&As[cur][k][m0+4];
      const float4 b01 = *(const float4*)&Bs[cur][k][n0];     // guaranteed b128
      const float4 b23 = *(const float4*)&Bs[cur][k][n0+4];   // guaranteed b128
      f32x2 b[4];
      b[0] = (f32x2){b01.x, b01.y}; b[1] = (f32x2){b01.z, b01.w};
      b[2] = (f32x2){b23.x, b23.y}; b[3] = (f32x2){b23.z, b23.w};
#pragma unroll
      for (int i = 0; i < 8; ++i) {
        const f32x2 ai = (f32x2){a[i], a[i]};
#pragma unroll
        for (int j = 0; j < 4; ++j)
          acc[i][j] = __builtin_elementwise_fma(ai, b[j], acc[i][j]);
      }
    }
  }
#pragma unroll
  for (int i = 0; i < 8; ++i) {
    float* dst = Cp + (size_t)(m0+i)*DD + nt*128 + n0;
    *(float4*)dst     = make_float4(acc[i][0].x, acc[i][0].y, acc[i][1].x, acc[i][1].y);
    *(float4*)(dst+4) = make_float4(acc[i][2].x, acc[i][2].y, acc[i][3].x, acc[i][3].y);
  }
}

// ---------------- S2 = 2*(sum_64 slabs - h), emit 2-way splits ----------------
__global__ __launch_bounds__(256) void k_reduce_S2s(const float* __restrict__ X,
    const float* __restrict__ h,
    ushort* __restrict__ s0, ushort* __restrict__ s1)
{
  const size_t off = ((size_t)blockIdx.x * 256 + threadIdx.x) * 2;
  f32x2 s = (f32x2){0.f, 0.f};
#pragma unroll 4
  for (int k = 0; k < FWD_SLABS; ++k) {
    const f32x2 c = *(const f32x2*)(X + (size_t)k * CN + off);
    s.x += c.x; s.y += c.y;
  }
  const f32x2 hh = *(const f32x2*)(h + off);
  float v0 = 2.f*(s.x-hh.x), v1 = 2.f*(s.y-hh.y);
  ushort a0, b0, a1, b1;
  split2(v0, a0, b0); split2(v1, a1, b1);
  *(ushort2*)(s0 + off) = make_ushort2(a0, a1);
  *(ushort2*)(s1 + off) = make_ushort2(b0, b1);
}

// ---------------- bwd 3-product MFMA + fused w-weighted row partials ----------------
// dw(slab) = S2 @ H^T ; rpart[row][ks*256+bn] (transposed); w = e * sscale[row]
__global__ __launch_bounds__(256, 2) void k_gemm3_bwd(
    const ushort* __restrict__ A0, const ushort* __restrict__ A1,
    const ushort* __restrict__ B0, const ushort* __restrict__ B1,
    const float* __restrict__ e,
    const float* __restrict__ pmx, const float* __restrict__ psm,
    float* __restrict__ C, float* __restrict__ rpart)
{
  __shared__ ushort lds[12288];   // A: 2*[128][32] ; B: 2*[64][32]
  __shared__ float rbuf[128][33];
  __shared__ float sscale[128];
  const int tid = threadIdx.x;
  const int lane = tid & 63, wid = tid >> 6;
  const int wm = (wid >> 1) * 64, wn = (wid & 1) * 32;
  const int bn = blockIdx.x, ks = blockIdx.y;
  const int n0 = bn * 64;
  const int chunk = n0 >> 11;
  const int kbase = ks * 512;
  C += (size_t)ks * PN;

  if (tid < 128) {
    float mx, inv; combine_stats(pmx, psm, tid, mx, inv);
    sscale[tid] = expf(pmx[chunk*128 + tid] - mx) * inv;
  }

  const ushort* Ap[2] = {A0, A1};
  const ushort* Bp[2] = {B0, B1};

  f32x4v acc[4][2];
#pragma unroll
  for (int i = 0; i < 4; ++i)
#pragma unroll
    for (int j = 0; j < 2; ++j) acc[i][j] = (f32x4v){0.f, 0.f, 0.f, 0.f};

  for (int kt = 0; kt < 16; ++kt) {
    const int kpos = kbase + (kt << 5);
#pragma unroll
    for (int c = 0; c < 4; ++c) {
      const int L = c*256 + tid;
      const int s = L >> 9, rr = L & 511;
      const int row = rr >> 2, slot = rr & 3;
      const int sl = slot ^ ((row >> 1) & 3);
      const ushort* src = Ap[s] + (size_t)row * DD + kpos + (sl << 3);
      __builtin_amdgcn_global_load_lds((const __attribute__((address_space(1))) void*)src,
          (__attribute__((address_space(3))) void*)&lds[(size_t)(c*256 + (wid << 6)) * 8], 16, 0, 0);
    }
#pragma unroll
    for (int c = 0; c < 2; ++c) {
      const int L = c*256 + tid;
      const int s = L >> 8, rr = L & 255;
      const int row = rr >> 2, slot = rr & 3;
      const int sl = slot ^ ((row >> 1) & 3);
      const ushort* src = Bp[s] + (size_t)(n0 + row) * DD + kpos + (sl << 3);
      __builtin_amdgcn_global_load_lds((const __attribute__((address_space(1))) void*)src,
          (__attribute__((address_space(3))) void*)&lds[8192 + (size_t)(c*256 + (wid << 6)) * 8], 16, 0, 0);
    }
    __syncthreads();

    bf16x8 bf[2][2];
#pragma unroll
    for (int s = 0; s < 2; ++s)
#pragma unroll
      for (int j = 0; j < 2; ++j) {
        const int n = wn + j*16 + (lane & 15);
        const int sl = (lane >> 4) ^ ((n >> 1) & 3);
        bf[s][j] = *(const bf16x8*)&lds[8192 + s*2048 + n*32 + sl*8];
      }
#pragma unroll
    for (int sa = 0; sa < 2; ++sa) {
      bf16x8 af[4];
#pragma unroll
      for (int i = 0; i < 4; ++i) {
        const int mrow = wm + i*16 + (lane & 15);
        const int sl = (lane >> 4) ^ ((mrow >> 1) & 3);
        af[i] = *(const bf16x8*)&lds[sa*4096 + mrow*32 + sl*8];
      }
#pragma unroll
      for (int sb = 0; sb < 2 - sa; ++sb)
#pragma unroll
        for (int i = 0; i < 4; ++i)
#pragma unroll
          for (int j = 0; j < 2; ++j)
            acc[i][j] = __builtin_amdgcn_mfma_f32_16x16x32_bf16(af[i], bf[sb][j], acc[i][j], 0, 0, 0);
    }
    __syncthreads();
  }
  // epilogue: store dw slab + fused w-weighted row partials
#pragma unroll
  for (int i = 0; i < 4; ++i) {
    const int rbase = wm + i*16 + ((lane >> 4) << 2);
#pragma unroll
    for (int r = 0; r < 4; ++r) {
      const int row = rbase + r;
      const float sc = sscale[row];
      float s = 0.f;
#pragma unroll
      for (int j = 0; j < 2; ++j) {
        const int cg = n0 + wn + j*16 + (lane & 15);
        C[(size_t)row * NTR + cg] = acc[i][j][r];
        s = fmaf(e[(size_t)row * NTR + cg] * sc, acc[i][j][r], s);
      }
      rbuf[row][((wn >> 5) << 4) + (lane & 15)] = s;
    }
  }
  __syncthreads();
  if (tid < 128) {
    float s = 0.f;
#pragma unroll
    for (int t = 0; t < 32; ++t) s += rbuf[tid][t];
    rpart[(size_t)tid * 512 + ks*256 + bn] = s;
  }
}

// ---------------- Adam: w = e*scale on the fly; updates p,m,v; writes e-new + stats ----------------
__global__ __launch_bounds__(256) void k_adam_f(float* __restrict__ pp_,
    float* __restrict__ m, float* __restrict__ v,
    float* __restrict__ e, const float* __restrict__ X,
    const float* __restrict__ rpart,
    const float* __restrict__ pmx_in, const float* __restrict__ psm_in,
    float* __restrict__ pmx_out, float* __restrict__ psm_out,
    float bc1, float bc2)
{
  const int bid = blockIdx.x, tid = threadIdx.x;
  const int row = bid >> 3, chunk = bid & 7;
  float mx, inv; combine_stats(pmx_in, psm_in, row, mx, inv);
  const float sc = expf(pmx_in[chunk*128 + row] - mx) * inv;   // w_old = e_old * sc
  __shared__ float red[256];
  red[tid] = rpart[(size_t)row*512 + tid] + rpart[(size_t)row*512 + 256 + tid];
  __syncthreads();
  for (int s = 128; s > 0; s >>= 1) { if (tid < s) red[tid] += red[tid+s]; __syncthreads(); }
  const float rr = red[0];
  const size_t base = (size_t)bid * 2048 + tid * 4;
  float pn[8];
#pragma unroll
  for (int part = 0; part < 2; ++part) {
    const size_t off = base + part * 1024;
    float4 u  = *(const float4*)(X + off);
    const float4 u1 = *(const float4*)(X + (size_t)PN + off);
    u.x += u1.x; u.y += u1.y; u.z += u1.z; u.w += u1.w;
    const float4 e4 = *(const float4*)(e + off);
    const float wv[4] = {e4.x*sc, e4.y*sc, e4.z*sc, e4.w*sc};
    const float uu[4] = {u.x, u.y, u.z, u.w};
    float4 p4 = *(float4*)(pp_ + off);
    float4 m4 = *(float4*)(m + off);
    float4 v4 = *(float4*)(v + off);
    float* pp = (float*)&p4; float* mm = (float*)&m4; float* vv = (float*)&v4;
#pragma unroll
    for (int e2 = 0; e2 < 4; ++e2) {
      const float g  = wv[e2] * (uu[e2] - rr);
      const float mn = 0.9f*mm[e2] + 0.1f*g;
      const float vn = 0.999f*vv[e2] + 0.001f*(g*g);
      const float mh = mn / bc1, vh = vn / bc2;
      pp[e2] = pp[e2] - 1e-3f * mh / (sqrtf(vh) + 1e-8f);
      mm[e2] = mn; vv[e2] = vn;
      pn[part*4 + e2] = pp[e2];
    }
    *(float4*)(pp_ + off) = p4;
    *(float4*)(m + off) = m4;
    *(float4*)(v + off) = v4;
  }
  // new chunk stats + e-new over the 2048 updated p values
  float lmx = pn[0];
#pragma unroll
  for (int e2 = 1; e2 < 8; ++e2) lmx = fmaxf(lmx, pn[e2]);
  __syncthreads();
  red[tid] = lmx; __syncthreads();
  for (int s = 128; s > 0; s >>= 1) { if (tid < s) red[tid] = fmaxf(red[tid], red[tid+s]); __syncthreads(); }
  const float bmx = red[0]; __syncthreads();
  float en[8];
  float ls = 0.f;
#pragma unroll
  for (int e2 = 0; e2 < 8; ++e2) { en[e2] = expf(pn[e2] - bmx); ls += en[e2]; }
#pragma unroll
  for (int part = 0; part < 2; ++part) {
    const size_t off = base + part * 1024;
    *(float4*)(e + off) = make_float4(en[part*4+0], en[part*4+1], en[part*4+2], en[part*4+3]);
  }
  red[tid] = ls; __syncthreads();
  for (int s = 128; s > 0; s >>= 1) { if (tid < s) red[tid] += red[tid+s]; __syncthreads(); }
  if (tid == 0) {
    pmx_out[chunk*128 + row] = bmx;
    psm_out[chunk*128 + row] = red[0];
  }
}

extern "C" void kernel_launch(void* const* d_in, const int* in_sizes, int n_in,
                              void* d_out, int out_size, void* d_ws, size_t ws_size,
                              hipStream_t stream) {
  const float* h = (const float*)d_in[0];
  const float* H = (const float*)d_in[1];
  (void)in_sizes; (void)n_in; (void)out_size; (void)ws_size;
  const int n_epoch = 1000;

  // floats: p,m,v (3PN) + e (PN) + X (4PN) + rpart (128*512) + stats A/B (4*1024)
  // ushorts: s-splits (2CN) + H-splits (2HN)
  float* p  = (float*)d_ws;
  float* m  = p + PN;
  float* v  = m + PN;
  float* e  = v + PN;
  float* X  = e + PN;
  float* rp = X + (size_t)4*PN;          // 128*512
  float* pmxA = rp + 128*512;            // 1024 each
  float* psmA = pmxA + 1024;
  float* pmxB = psmA + 1024;
  float* psmB = pmxB + 1024;
  ushort* s0 = (ushort*)(psmB + 1024);
  ushort* s1 = s0 + CN;
  ushort* H0 = s1 + CN, *H1 = H0 + HN;

  hipMemsetAsync(p, 0, (size_t)3*PN*sizeof(float), stream);
  k_prep<<<HN/1024, 256, 0, stream>>>(H, H0, H1);
  k_stat0<<<4, 256, 0, stream>>>(pmxA, psmA);
  k_einit<<<PN/2048, 256, 0, stream>>>(e);

  for (int s = 1; s <= n_epoch; ++s) {
    float* pmx_in  = (s & 1) ? pmxA : pmxB;
    float* psm_in  = (s & 1) ? psmA : psmB;
    float* pmx_out = (s & 1) ? pmxB : pmxA;
    float* psm_out = (s & 1) ? psmB : psmA;
    k_fwd_v<<<dim3(8, FWD_SLABS), 256, 0, stream>>>(e, pmx_in, psm_in, H, X);
    k_reduce_S2s<<<CN/512, 256, 0, stream>>>(X, h, s0, s1);
    k_gemm3_bwd<<<dim3(256, BWD_SLABS), 256, 0, stream>>>(s0, s1, H0, H1, e, pmx_in, psm_in, X, rp);
    const float bc1 = 1.0f - powf(0.9f,   (float)s);
    const float bc2 = 1.0f - powf(0.999f, (float)s);
    k_adam_f<<<1024, 256, 0, stream>>>(p, m, v, e, X, rp, pmx_in, psm_in, pmx_out, psm_out, bc1, bc2);
  }
  k_softmax_f<<<BB, 512, 0, stream>>>(p, (float*)d_out);
}